// Round 13
// baseline (130.791 us; speedup 1.0000x reference)
//
#include <hip/hip_runtime.h>
#include <hip/hip_bf16.h>
#include <stdint.h>

// CA model: B=8, H=256, W=256, C=16, HID=128, steps=2 (fixed by setup_inputs).
// Round 13: perceive folded into MFMA. W0' composes identity+sobel over the
// 3x3 neighborhood: K = 160 (9 taps x 16ch + bias/pad chunk, bias at k=144).
// xs staged as bf16; each GEMM1 B-fragment (k-chunk q) is ONE ds_read_b128 at
// tap t=2q+(g>>1), half g&1 (k=32q+8g+j => t=k>>4, ch=8(g&1)+j). Sobel VALU,
// a0/a1 packing and fp32 tap reads deleted. Residual x re-read from global
// (coalesced, L2-hot). GEMM2 tau-permuted as rounds 8-12.

#define NB 8
#define NH 256
#define NW 256
#define NC 16
#define WOFF 65536   // tmp offset in d_ws when prep region in use (45KB used)

typedef __attribute__((ext_vector_type(8))) short short8;
typedef __attribute__((ext_vector_type(4))) float floatx4;

__host__ __device__ inline void tf2x32(uint32_t k0, uint32_t k1,
                                       uint32_t x0, uint32_t x1,
                                       uint32_t& o0, uint32_t& o1) {
  const uint32_t ks2 = k0 ^ k1 ^ 0x1BD11BDAu;
  x0 += k0; x1 += k1;
#define RL(v, d) (((v) << (d)) | ((v) >> (32 - (d))))
#define R4(a, b, c, d)                          \
  x0 += x1; x1 = RL(x1, a); x1 ^= x0;           \
  x0 += x1; x1 = RL(x1, b); x1 ^= x0;           \
  x0 += x1; x1 = RL(x1, c); x1 ^= x0;           \
  x0 += x1; x1 = RL(x1, d); x1 ^= x0;
  R4(13, 15, 26, 6);  x0 += k1;  x1 += ks2 + 1u;
  R4(17, 29, 16, 24); x0 += ks2; x1 += k0 + 2u;
  R4(13, 15, 26, 6);  x0 += k0;  x1 += k1 + 3u;
  R4(17, 29, 16, 24); x0 += k1;  x1 += ks2 + 4u;
  R4(13, 15, 26, 6);  x0 += ks2; x1 += k0 + 5u;
#undef R4
#undef RL
  o0 = x0; o1 = x1;
}

__device__ inline short bfr(float x) {
  __hip_bfloat16 h = __float2bfloat16(x);
  return *reinterpret_cast<short*>(&h);
}

// composed W0' element: k = 16t+ch; taps t=0..8 row-major (dh,dw); t=9: bias/pad
__device__ inline float w0comp(const float* __restrict__ W0,
                               const float* __restrict__ b0, int o, int k) {
  const int t = k >> 4;
  const int ch = k & 15;
  if (t == 9) return (ch == 0) ? b0[o] : 0.f;   // k==144 -> bias, rest 0
  const int dh = t / 3 - 1, dw = t % 3 - 1;
  const float Ac[3] = {1.f, 2.f, 1.f};
  const float Bc[3] = {-1.f, 0.f, 1.f};
  float v = (t == 4) ? W0[o * 48 + ch] : 0.f;                     // identity
  v += Ac[dw + 1] * Bc[dh + 1] * 0.125f * W0[o * 48 + 16 + ch];   // c1 (sobel1)
  v += Ac[dh + 1] * Bc[dw + 1] * 0.125f * W0[o * 48 + 32 + ch];   // c2 (sobel2)
  return v;
}

// ---- one-block prep: per-lane fragments of W0'(K=160) and tau-permuted W1 ----
__global__ __launch_bounds__(64) void ca_prep(
    const float* __restrict__ W0, const float* __restrict__ b0,
    const float* __restrict__ W1, short* __restrict__ wbuf) {
  const int lane = threadIdx.x;
  const int c15 = lane & 15;
  const int g = lane >> 4;
  short8* wf = reinterpret_cast<short8*>(wbuf);

  for (int n = 0; n < 8; ++n)
    for (int q = 0; q < 5; ++q) {
      short8 f;
#pragma unroll
      for (int j = 0; j < 8; ++j)
        f[j] = bfr(w0comp(W0, b0, 16 * n + c15, 32 * q + 8 * g + j));
      wf[(n * 5 + q) * 64 + lane] = f;
    }
  // GEMM2' fragments, tau(s,8g+j)=32s+16*(j>>2)+4g+(j&3)
#pragma unroll
  for (int s = 0; s < 4; ++s) {
    const float* p = W1 + c15 * 128;
    short8 f;
#pragma unroll
    for (int j = 0; j < 8; ++j)
      f[j] = bfr(p[32 * s + 16 * (j >> 2) + 4 * g + (j & 3)]);
    wf[(40 + s) * 64 + lane] = f;
  }
}

template <bool PRE>
__global__ __launch_bounds__(64, 2) void ca_step(
    const float* __restrict__ xin, float* __restrict__ xout,
    const float* __restrict__ W0, const float* __restrict__ b0,
    const float* __restrict__ W1, const short* __restrict__ wfrag,
    uint32_t fk0, uint32_t fk1) {
  // bf16 x tile + halo: 6 rows x 18 cols x 16 ch, linear (reads ~contiguous)
  __shared__ __align__(16) uint16_t xs[6 * 18 * 16];

  const int tid = threadIdx.x;
  const int bt = blockIdx.x;
  const int wt = bt & 15;
  const int ht8 = (bt >> 4) & 31;
  const int b = bt >> 9;
  const int h0 = ht8 * 8;
  const int w0 = wt * 16;

  const int lane = tid;
  const int c15 = lane & 15;
  const int g = lane >> 4;
  const int hh0 = g & 1;      // channel-half this lane supplies to B
  const int thalf = g >> 1;

  // ---- weight fragments (held in VGPRs for whole kernel) ----
  short8 w0f[8][5];
  short8 w1f[4];
  if constexpr (PRE) {
    const short8* wf = reinterpret_cast<const short8*>(wfrag);
#pragma unroll
    for (int n = 0; n < 8; ++n)
#pragma unroll
      for (int q = 0; q < 5; ++q) w0f[n][q] = wf[(n * 5 + q) * 64 + lane];
#pragma unroll
    for (int s = 0; s < 4; ++s) w1f[s] = wf[(40 + s) * 64 + lane];
  } else {
    for (int n = 0; n < 8; ++n)
      for (int q = 0; q < 5; ++q) {
        short8 f;
#pragma unroll
        for (int j = 0; j < 8; ++j)
          f[j] = bfr(w0comp(W0, b0, 16 * n + c15, 32 * q + 8 * g + j));
        w0f[n][q] = f;
      }
#pragma unroll
    for (int s = 0; s < 4; ++s) {
      const float* p = W1 + c15 * 128;
      short8 f;
#pragma unroll
      for (int j = 0; j < 8; ++j)
        f[j] = bfr(p[32 * s + 16 * (j >> 2) + 4 * g + (j & 3)]);
      w1f[s] = f;
    }
  }

  // per-q tap offsets (uint16 elements, relative to center cell element idx)
  int doff[5];
#pragma unroll
  for (int q = 0; q < 5; ++q) {
    int t = 2 * q + thalf;
    if (t > 8) t = 8;                       // q=4,g>=2: frag replaced by cb
    const int dh = t / 3 - 1, dw = t % 3 - 1;
    doff[q] = (dh * 18 + dw) * 16;
  }
  // constant bias fragment for q=4, g>=2: B[k=144]=1 adds b0[o]
  short8 cb;
#pragma unroll
  for (int j = 0; j < 8; ++j) cb[j] = 0;
  if (g == 2) cb[0] = bfr(1.0f);

#pragma unroll 1
  for (int t2 = 0; t2 < 2; ++t2) {
    const int h0t = h0 + 4 * t2;

    __syncthreads();   // WAR: prior tile's xs reads drain before re-staging

    // ---- stage bf16 x tile (zero-padded halo): 216 16B-halves ----
    for (int f = tid; f < 216; f += 64) {
      const int row = f / 36;
      const int rem = f - row * 36;
      const int col = rem >> 1;
      const int hx = rem & 1;
      const int gh = h0t - 1 + row;
      const int gw = w0 - 1 + col;
      short8 v;
#pragma unroll
      for (int j = 0; j < 8; ++j) v[j] = 0;
      if ((unsigned)gh < (unsigned)NH && (unsigned)gw < (unsigned)NW) {
        const float* p = xin + (((size_t)b * NH + gh) * NW + gw) * NC + 8 * hx;
        const floatx4 u0 = *reinterpret_cast<const floatx4*>(p);
        const floatx4 u1 = *reinterpret_cast<const floatx4*>(p + 4);
        v[0] = bfr(u0.x); v[1] = bfr(u0.y); v[2] = bfr(u0.z); v[3] = bfr(u0.w);
        v[4] = bfr(u1.x); v[5] = bfr(u1.y); v[6] = bfr(u1.z); v[7] = bfr(u1.w);
      }
      *reinterpret_cast<short8*>(&xs[(row * 18 + col) * 16 + hx * 8]) = v;
    }

    // ---- fire mask: lane -> (row=lane>>4, col=lane&15), bit = 16*row+col ----
    uint64_t mball;
    {
      const int cellg = (b * NH + h0t + (lane >> 4)) * NW + w0 + c15;
      uint32_t r0, r1;
      tf2x32(fk0, fk1, 0u, (uint32_t)cellg, r0, r1);
      const uint32_t bits = r0 ^ r1;
      const float u = __uint_as_float((bits >> 9) | 0x3F800000u) - 1.0f;
      mball = __ballot(u > 0.5f);
    }
    __syncthreads();   // staging drains before reads

#pragma unroll
    for (int mt = 0; mt < 4; ++mt) {
      // center cell element index in xs
      const int cidx = ((1 + mt) * 18 + 1 + c15) * 16 + hh0 * 8;

      // residual x (fp32) from global — coalesced, L2-hot; issue early
      const size_t cellg = ((size_t)(b * NH + h0t + mt)) * NW + w0 + c15;
      const floatx4 xv =
          *reinterpret_cast<const floatx4*>(xin + cellg * NC + 4 * g);

      // B-fragments: one b128 read per k-chunk
      short8 bq[5];
#pragma unroll
      for (int q = 0; q < 5; ++q)
        bq[q] = *reinterpret_cast<const short8*>(&xs[cidx + doff[q]]);
      if (g >= 2) bq[4] = cb;   // bias/pad chunk

      // GEMM1: 40 MFMAs; lane holds H^T[o=16n+4g+reg][cell=c15]
      floatx4 acc[8];
#pragma unroll
      for (int n = 0; n < 8; ++n) acc[n] = floatx4{0.f, 0.f, 0.f, 0.f};
#pragma unroll
      for (int q = 0; q < 5; ++q)
#pragma unroll
        for (int n = 0; n < 8; ++n)
          acc[n] =
              __builtin_amdgcn_mfma_f32_16x16x32_bf16(w0f[n][q], bq[q], acc[n], 0, 0, 0);

      // GEMM2: B-frag is the lane's own relu'd accumulators (tau-permuted)
      floatx4 acc2 = {0.f, 0.f, 0.f, 0.f};
#pragma unroll
      for (int s = 0; s < 4; ++s) {
        short8 b2;
#pragma unroll
        for (int j = 0; j < 8; ++j)
          b2[j] = bfr(fmaxf(acc[2 * s + (j >> 2)][j & 3], 0.f));
        acc2 = __builtin_amdgcn_mfma_f32_16x16x32_bf16(w1f[s], b2, acc2, 0, 0, 0);
      }

      // update: lane holds dx[ch=4g+reg][cell=c15]; fp32 residual path
      const float mk = (float)((mball >> (16 * mt + c15)) & 1ull);
      const float mk03 = (g == 0) ? 0.f : mk;   // channels 0..2 frozen
      floatx4 ov;
      ov.x = xv.x + acc2.x * mk03;
      ov.y = xv.y + acc2.y * mk03;
      ov.z = xv.z + acc2.z * mk03;
      ov.w = xv.w + acc2.w * mk;
      *reinterpret_cast<floatx4*>(xout + cellg * NC + 4 * g) = ov;
    }
  }
}

extern "C" void kernel_launch(void* const* d_in, const int* in_sizes, int n_in,
                              void* d_out, int out_size, void* d_ws, size_t ws_size,
                              hipStream_t stream) {
  const float* x  = (const float*)d_in[0];
  const float* W0 = (const float*)d_in[1];
  const float* b0 = (const float*)d_in[2];
  const float* W1 = (const float*)d_in[3];
  float* out = (float*)d_out;

  const size_t tmp_bytes = (size_t)NB * NH * NW * NC * 4;   // 32 MiB
  const bool pre = ws_size >= (size_t)WOFF + tmp_bytes;
  short* wbuf = (short*)d_ws;
  float* tmp = pre ? (float*)((char*)d_ws + WOFF) : (float*)d_ws;

  uint32_t fa0, fa1, fb0, fb1;
  tf2x32(0u, 42u, 0u, 0u, fa0, fa1);  // fold_in(key(42), 0)
  tf2x32(0u, 42u, 0u, 1u, fb0, fb1);  // fold_in(key(42), 1)

  dim3 grid(NB * (NH / 8) * (NW / 16)), block(64);
  if (pre) {
    ca_prep<<<1, 64, 0, stream>>>(W0, b0, W1, wbuf);
    ca_step<true><<<grid, block, 0, stream>>>(x, tmp, W0, b0, W1, wbuf, fa0, fa1);
    ca_step<true><<<grid, block, 0, stream>>>(tmp, out, W0, b0, W1, wbuf, fb0, fb1);
  } else {
    ca_step<false><<<grid, block, 0, stream>>>(x, tmp, W0, b0, W1, nullptr, fa0, fa1);
    ca_step<false><<<grid, block, 0, stream>>>(tmp, out, W0, b0, W1, nullptr, fb0, fb1);
  }
}

// Round 14
// 72.467 us; speedup vs baseline: 1.8048x; 1.8048x over previous
//
#include <hip/hip_runtime.h>
#include <hip/hip_bf16.h>
#include <stdint.h>

// CA model: B=8, H=256, W=256, C=16, HID=128, steps=2 (fixed by setup_inputs).
// Round 14: parallel prep. Round-13's fused-perceive ca_step is kept
// byte-identical (W0' composes identity+sobel, K=160, one ds_read_b128 per
// B-fragment, tau-permuted GEMM2). ca_prep was a single 64-thread wave doing
// ~960 serial scalar loads (65 us!); now 44 blocks x 64 lanes, one fragment
// per block (~2-4 us).

#define NB 8
#define NH 256
#define NW 256
#define NC 16
#define WOFF 65536   // tmp offset in d_ws when prep region in use (45KB used)

typedef __attribute__((ext_vector_type(8))) short short8;
typedef __attribute__((ext_vector_type(4))) float floatx4;

__host__ __device__ inline void tf2x32(uint32_t k0, uint32_t k1,
                                       uint32_t x0, uint32_t x1,
                                       uint32_t& o0, uint32_t& o1) {
  const uint32_t ks2 = k0 ^ k1 ^ 0x1BD11BDAu;
  x0 += k0; x1 += k1;
#define RL(v, d) (((v) << (d)) | ((v) >> (32 - (d))))
#define R4(a, b, c, d)                          \
  x0 += x1; x1 = RL(x1, a); x1 ^= x0;           \
  x0 += x1; x1 = RL(x1, b); x1 ^= x0;           \
  x0 += x1; x1 = RL(x1, c); x1 ^= x0;           \
  x0 += x1; x1 = RL(x1, d); x1 ^= x0;
  R4(13, 15, 26, 6);  x0 += k1;  x1 += ks2 + 1u;
  R4(17, 29, 16, 24); x0 += ks2; x1 += k0 + 2u;
  R4(13, 15, 26, 6);  x0 += k0;  x1 += k1 + 3u;
  R4(17, 29, 16, 24); x0 += k1;  x1 += ks2 + 4u;
  R4(13, 15, 26, 6);  x0 += ks2; x1 += k0 + 5u;
#undef R4
#undef RL
  o0 = x0; o1 = x1;
}

__device__ inline short bfr(float x) {
  __hip_bfloat16 h = __float2bfloat16(x);
  return *reinterpret_cast<short*>(&h);
}

// composed W0' element: k = 16t+ch; taps t=0..8 row-major (dh,dw); t=9: bias/pad
__device__ inline float w0comp(const float* __restrict__ W0,
                               const float* __restrict__ b0, int o, int k) {
  const int t = k >> 4;
  const int ch = k & 15;
  if (t == 9) return (ch == 0) ? b0[o] : 0.f;   // k==144 -> bias, rest 0
  const int dh = t / 3 - 1, dw = t % 3 - 1;
  const float Ac[3] = {1.f, 2.f, 1.f};
  const float Bc[3] = {-1.f, 0.f, 1.f};
  float v = (t == 4) ? W0[o * 48 + ch] : 0.f;                     // identity
  v += Ac[dw + 1] * Bc[dh + 1] * 0.125f * W0[o * 48 + 16 + ch];   // c1 (sobel1)
  v += Ac[dh + 1] * Bc[dw + 1] * 0.125f * W0[o * 48 + 32 + ch];   // c2 (sobel2)
  return v;
}

// ---- parallel prep: 44 blocks x 64 lanes, one fragment per block ----
__global__ __launch_bounds__(64) void ca_prep(
    const float* __restrict__ W0, const float* __restrict__ b0,
    const float* __restrict__ W1, short* __restrict__ wbuf) {
  const int lane = threadIdx.x;
  const int c15 = lane & 15;
  const int g = lane >> 4;
  const int fi = blockIdx.x;   // 0..43
  short8 f;
  if (fi < 40) {
    const int n = fi / 5, q = fi - 5 * n;
#pragma unroll
    for (int j = 0; j < 8; ++j)
      f[j] = bfr(w0comp(W0, b0, 16 * n + c15, 32 * q + 8 * g + j));
  } else {
    const int s = fi - 40;   // tau(s,8g+j)=32s+16*(j>>2)+4g+(j&3)
    const float* p = W1 + c15 * 128;
#pragma unroll
    for (int j = 0; j < 8; ++j)
      f[j] = bfr(p[32 * s + 16 * (j >> 2) + 4 * g + (j & 3)]);
  }
  reinterpret_cast<short8*>(wbuf)[fi * 64 + lane] = f;
}

template <bool PRE>
__global__ __launch_bounds__(64, 2) void ca_step(
    const float* __restrict__ xin, float* __restrict__ xout,
    const float* __restrict__ W0, const float* __restrict__ b0,
    const float* __restrict__ W1, const short* __restrict__ wfrag,
    uint32_t fk0, uint32_t fk1) {
  // bf16 x tile + halo: 6 rows x 18 cols x 16 ch, linear (reads ~contiguous)
  __shared__ __align__(16) uint16_t xs[6 * 18 * 16];

  const int tid = threadIdx.x;
  const int bt = blockIdx.x;
  const int wt = bt & 15;
  const int ht8 = (bt >> 4) & 31;
  const int b = bt >> 9;
  const int h0 = ht8 * 8;
  const int w0 = wt * 16;

  const int lane = tid;
  const int c15 = lane & 15;
  const int g = lane >> 4;
  const int hh0 = g & 1;      // channel-half this lane supplies to B
  const int thalf = g >> 1;

  // ---- weight fragments (held in VGPRs for whole kernel) ----
  short8 w0f[8][5];
  short8 w1f[4];
  if constexpr (PRE) {
    const short8* wf = reinterpret_cast<const short8*>(wfrag);
#pragma unroll
    for (int n = 0; n < 8; ++n)
#pragma unroll
      for (int q = 0; q < 5; ++q) w0f[n][q] = wf[(n * 5 + q) * 64 + lane];
#pragma unroll
    for (int s = 0; s < 4; ++s) w1f[s] = wf[(40 + s) * 64 + lane];
  } else {
    for (int n = 0; n < 8; ++n)
      for (int q = 0; q < 5; ++q) {
        short8 f;
#pragma unroll
        for (int j = 0; j < 8; ++j)
          f[j] = bfr(w0comp(W0, b0, 16 * n + c15, 32 * q + 8 * g + j));
        w0f[n][q] = f;
      }
#pragma unroll
    for (int s = 0; s < 4; ++s) {
      const float* p = W1 + c15 * 128;
      short8 f;
#pragma unroll
      for (int j = 0; j < 8; ++j)
        f[j] = bfr(p[32 * s + 16 * (j >> 2) + 4 * g + (j & 3)]);
      w1f[s] = f;
    }
  }

  // per-q tap offsets (uint16 elements, relative to center cell element idx)
  int doff[5];
#pragma unroll
  for (int q = 0; q < 5; ++q) {
    int t = 2 * q + thalf;
    if (t > 8) t = 8;                       // q=4,g>=2: frag replaced by cb
    const int dh = t / 3 - 1, dw = t % 3 - 1;
    doff[q] = (dh * 18 + dw) * 16;
  }
  // constant bias fragment for q=4, g>=2: B[k=144]=1 adds b0[o]
  short8 cb;
#pragma unroll
  for (int j = 0; j < 8; ++j) cb[j] = 0;
  if (g == 2) cb[0] = bfr(1.0f);

#pragma unroll 1
  for (int t2 = 0; t2 < 2; ++t2) {
    const int h0t = h0 + 4 * t2;

    __syncthreads();   // WAR: prior tile's xs reads drain before re-staging

    // ---- stage bf16 x tile (zero-padded halo): 216 16B-halves ----
    for (int f = tid; f < 216; f += 64) {
      const int row = f / 36;
      const int rem = f - row * 36;
      const int col = rem >> 1;
      const int hx = rem & 1;
      const int gh = h0t - 1 + row;
      const int gw = w0 - 1 + col;
      short8 v;
#pragma unroll
      for (int j = 0; j < 8; ++j) v[j] = 0;
      if ((unsigned)gh < (unsigned)NH && (unsigned)gw < (unsigned)NW) {
        const float* p = xin + (((size_t)b * NH + gh) * NW + gw) * NC + 8 * hx;
        const floatx4 u0 = *reinterpret_cast<const floatx4*>(p);
        const floatx4 u1 = *reinterpret_cast<const floatx4*>(p + 4);
        v[0] = bfr(u0.x); v[1] = bfr(u0.y); v[2] = bfr(u0.z); v[3] = bfr(u0.w);
        v[4] = bfr(u1.x); v[5] = bfr(u1.y); v[6] = bfr(u1.z); v[7] = bfr(u1.w);
      }
      *reinterpret_cast<short8*>(&xs[(row * 18 + col) * 16 + hx * 8]) = v;
    }

    // ---- fire mask: lane -> (row=lane>>4, col=lane&15), bit = 16*row+col ----
    uint64_t mball;
    {
      const int cellg = (b * NH + h0t + (lane >> 4)) * NW + w0 + c15;
      uint32_t r0, r1;
      tf2x32(fk0, fk1, 0u, (uint32_t)cellg, r0, r1);
      const uint32_t bits = r0 ^ r1;
      const float u = __uint_as_float((bits >> 9) | 0x3F800000u) - 1.0f;
      mball = __ballot(u > 0.5f);
    }
    __syncthreads();   // staging drains before reads

#pragma unroll
    for (int mt = 0; mt < 4; ++mt) {
      // center cell element index in xs
      const int cidx = ((1 + mt) * 18 + 1 + c15) * 16 + hh0 * 8;

      // residual x (fp32) from global — coalesced, L2-hot; issue early
      const size_t cellg = ((size_t)(b * NH + h0t + mt)) * NW + w0 + c15;
      const floatx4 xv =
          *reinterpret_cast<const floatx4*>(xin + cellg * NC + 4 * g);

      // B-fragments: one b128 read per k-chunk
      short8 bq[5];
#pragma unroll
      for (int q = 0; q < 5; ++q)
        bq[q] = *reinterpret_cast<const short8*>(&xs[cidx + doff[q]]);
      if (g >= 2) bq[4] = cb;   // bias/pad chunk

      // GEMM1: 40 MFMAs; lane holds H^T[o=16n+4g+reg][cell=c15]
      floatx4 acc[8];
#pragma unroll
      for (int n = 0; n < 8; ++n) acc[n] = floatx4{0.f, 0.f, 0.f, 0.f};
#pragma unroll
      for (int q = 0; q < 5; ++q)
#pragma unroll
        for (int n = 0; n < 8; ++n)
          acc[n] =
              __builtin_amdgcn_mfma_f32_16x16x32_bf16(w0f[n][q], bq[q], acc[n], 0, 0, 0);

      // GEMM2: B-frag is the lane's own relu'd accumulators (tau-permuted)
      floatx4 acc2 = {0.f, 0.f, 0.f, 0.f};
#pragma unroll
      for (int s = 0; s < 4; ++s) {
        short8 b2;
#pragma unroll
        for (int j = 0; j < 8; ++j)
          b2[j] = bfr(fmaxf(acc[2 * s + (j >> 2)][j & 3], 0.f));
        acc2 = __builtin_amdgcn_mfma_f32_16x16x32_bf16(w1f[s], b2, acc2, 0, 0, 0);
      }

      // update: lane holds dx[ch=4g+reg][cell=c15]; fp32 residual path
      const float mk = (float)((mball >> (16 * mt + c15)) & 1ull);
      const float mk03 = (g == 0) ? 0.f : mk;   // channels 0..2 frozen
      floatx4 ov;
      ov.x = xv.x + acc2.x * mk03;
      ov.y = xv.y + acc2.y * mk03;
      ov.z = xv.z + acc2.z * mk03;
      ov.w = xv.w + acc2.w * mk;
      *reinterpret_cast<floatx4*>(xout + cellg * NC + 4 * g) = ov;
    }
  }
}

extern "C" void kernel_launch(void* const* d_in, const int* in_sizes, int n_in,
                              void* d_out, int out_size, void* d_ws, size_t ws_size,
                              hipStream_t stream) {
  const float* x  = (const float*)d_in[0];
  const float* W0 = (const float*)d_in[1];
  const float* b0 = (const float*)d_in[2];
  const float* W1 = (const float*)d_in[3];
  float* out = (float*)d_out;

  const size_t tmp_bytes = (size_t)NB * NH * NW * NC * 4;   // 32 MiB
  const bool pre = ws_size >= (size_t)WOFF + tmp_bytes;
  short* wbuf = (short*)d_ws;
  float* tmp = pre ? (float*)((char*)d_ws + WOFF) : (float*)d_ws;

  uint32_t fa0, fa1, fb0, fb1;
  tf2x32(0u, 42u, 0u, 0u, fa0, fa1);  // fold_in(key(42), 0)
  tf2x32(0u, 42u, 0u, 1u, fb0, fb1);  // fold_in(key(42), 1)

  dim3 grid(NB * (NH / 8) * (NW / 16)), block(64);
  if (pre) {
    ca_prep<<<44, 64, 0, stream>>>(W0, b0, W1, wbuf);
    ca_step<true><<<grid, block, 0, stream>>>(x, tmp, W0, b0, W1, wbuf, fa0, fa1);
    ca_step<true><<<grid, block, 0, stream>>>(tmp, out, W0, b0, W1, wbuf, fb0, fb1);
  } else {
    ca_step<false><<<grid, block, 0, stream>>>(x, tmp, W0, b0, W1, nullptr, fa0, fa1);
    ca_step<false><<<grid, block, 0, stream>>>(tmp, out, W0, b0, W1, nullptr, fb0, fb1);
  }
}